// Round 2
// baseline (669.272 us; speedup 1.0000x reference)
//
#include <hip/hip_runtime.h>
#include <hip/hip_bf16.h>

typedef int v4i __attribute__((ext_vector_type(4)));

#define M_DIM 16384
#define N_DIM 4096
#define K_DIM 4096
#define BM 256
#define BN 256
#define BKB 128                 // K-bytes per tile
#define NT (K_DIM / BKB)        // 32 K-tiles

// ---------------- activation fake-quant: f32 -> i8 ----------------
__global__ void quant_x_kernel(const float4* __restrict__ x, int* __restrict__ q,
                               const float* __restrict__ act_scale, int n4) {
  const float s = fmaxf(act_scale[0], 1e-5f);
  int i = blockIdx.x * blockDim.x + threadIdx.x;
  const int stride = gridDim.x * blockDim.x;
  for (; i < n4; i += stride) {
    float4 v = x[i];
    int b0 = (int)fminf(fmaxf(rintf(v.x / s), -127.f), 127.f);
    int b1 = (int)fminf(fmaxf(rintf(v.y / s), -127.f), 127.f);
    int b2 = (int)fminf(fmaxf(rintf(v.z / s), -127.f), 127.f);
    int b3 = (int)fminf(fmaxf(rintf(v.w / s), -127.f), 127.f);
    q[i] = (b0 & 0xff) | ((b1 & 0xff) << 8) | ((b2 & 0xff) << 16) | ((b3 & 0xff) << 24);
  }
}

// ---------------- ternary weight repack: i32 {0,1,2} -> i8 {-1,0,1} ----------------
__global__ void pack_w_kernel(const int4* __restrict__ w, int* __restrict__ q, int n4) {
  int i = blockIdx.x * blockDim.x + threadIdx.x;
  const int stride = gridDim.x * blockDim.x;
  for (; i < n4; i += stride) {
    int4 v = w[i];
    q[i] = ((v.x - 1) & 0xff) | (((v.y - 1) & 0xff) << 8) |
           (((v.z - 1) & 0xff) << 16) | (((v.w - 1) & 0xff) << 24);
  }
}

// ---- i8 GEMM, THIS ROUND: A fragments DIRECT FROM GLOBAL (L2), B via LDS.
// r1 post-mortem: LDS pipe was the serial resource (256 ds ops = 3072cyc/tile
// vs MFMA 2611cyc); 128KiB of the 192KiB LDS reads were A wave-duplication
// (4 wn-sharing waves re-read each A panel). The 16x16x64 A-fragment global
// pattern is granule-perfect (lanes {l,l+16,l+32,l+48} = row l&15, bytes
// 0..63 => 16 contiguous 64B segments per wave-load, same granule count as a
// coalesced 1KiB load), and the XCD swizzle makes the 16 bn-sharing blocks of
// each A panel co-resident on one XCD => A frag loads hit XCD-local L2.
// A frags ping/pong per quarter (issue Q(q+1) before MFMA_Q(q): L2 hit
// ~225cyc < 326cyc MFMA quarter). LDS now holds only B (64KiB double-buffer):
// 96 ds ops/tile ~1150cyc, non-binding. MFMA pipe (2611cyc/tile) becomes the
// target floor. One lgkmcnt(0)+s_barrier per tile for the B-buffer flip;
// A-frag global loads deliberately stay in flight across it (T4).
__global__ __launch_bounds__(512, 2) void bitlinear_gemm(
    const signed char* __restrict__ A,   // [M][K] i8
    const signed char* __restrict__ B,   // [N][K] i8
    const float* __restrict__ bias,
    const float* __restrict__ alpha_p,
    const float* __restrict__ act_scale_p,
    float* __restrict__ out) {
  __shared__ __align__(16) signed char Bs[2][BN * BKB];   // 2 x 32 KiB (B only)

  const int t = threadIdx.x;
  const int lane = t & 63, wid = t >> 6;
  const int wm = wid >> 2, wn = wid & 3;       // 2M x 4N waves
  const int l15 = lane & 15, l4 = lane >> 4;

  // XCD-aware bijective swizzle (nwg=1024, divisible by 8)
  const int nwg = (M_DIM / BM) * (N_DIM / BN);
  const int wg = (blockIdx.x & 7) * (nwg >> 3) + (blockIdx.x >> 3);
  const int bm = wg / (N_DIM / BN);
  const int bn = wg % (N_DIM / BN);

  // ---- B reg-staging: LINEAR global loads, SWIZZLED ds_write ----
  const signed char* bGl = B + ((size_t)(bn * BN + (t >> 3))) * K_DIM + (t & 7) * 16;
  const int wrOff = (t >> 3) * 128 + (((t & 7) ^ ((t >> 3) & 7)) * 16);
  v4i sB[4];

#define GL_B(u, P) sB[u] = *(const v4i*)((P) + (size_t)((u) * 64) * K_DIM)
#define WR_B(BUF) { _Pragma("unroll") for (int u = 0; u < 4; ++u) \
    *(v4i*)&Bs[BUF][u * 8192 + wrOff] = sB[u]; }

  // ---- B fragment read addressing (zero-conflict XOR layout) ----
  const int l7 = l15 & 7;
  const int soK0 = ((0 + l4) ^ l7) * 16;   // kstep 0 chunk
  const int soK1 = ((4 + l4) ^ l7) * 16;   // kstep 1 chunk
  const int bRd = (wn * 64 + l15) * BKB;

  // ---- A fragment DIRECT addressing: lane l reads row (mi*16 + l&15),
  // bytes koff + (l>>4)*16. Identical element->lane mapping as the old LDS
  // path (row l15, kbyte l4*16 + kstep*64), so MFMA semantics are unchanged.
  const signed char* aBase = A + ((size_t)(bm * BM + wm * 128 + l15)) * K_DIM + l4 * 16;

  v4i aP[4], aQ[4];   // ping/pong A-fragment buffers (one quarter each)
  // AL(R, mi2, KOFF): load quarter {mi2, mi2+1} x {kstep0, kstep1}
#define AL(R, mi2, KOFF) \
  R[0] = *(const v4i*)(aBase + (size_t)(mi2) * 16 * K_DIM + (KOFF)); \
  R[1] = *(const v4i*)(aBase + (size_t)(mi2) * 16 * K_DIM + (KOFF) + 64); \
  R[2] = *(const v4i*)(aBase + (size_t)((mi2) + 1) * 16 * K_DIM + (KOFF)); \
  R[3] = *(const v4i*)(aBase + (size_t)((mi2) + 1) * 16 * K_DIM + (KOFF) + 64);

  v4i acc[8][4] = {};
  v4i bF[4][2];

#define LOAD_B(buf) \
  { _Pragma("unroll") for (int nc = 0; nc < 4; ++nc) { \
      bF[nc][0] = *(const v4i*)&Bs[buf][bRd + nc * 2048 + soK0]; \
      bF[nc][1] = *(const v4i*)&Bs[buf][bRd + nc * 2048 + soK1]; } }

#define MFMA_Q(q, R) \
  { _Pragma("unroll") for (int nc = 0; nc < 4; ++nc) { \
      acc[2*(q)][nc]   = __builtin_amdgcn_mfma_i32_16x16x64_i8(R[0], bF[nc][0], acc[2*(q)][nc], 0, 0, 0); \
      acc[2*(q)][nc]   = __builtin_amdgcn_mfma_i32_16x16x64_i8(R[1], bF[nc][1], acc[2*(q)][nc], 0, 0, 0); \
      acc[2*(q)+1][nc] = __builtin_amdgcn_mfma_i32_16x16x64_i8(R[2], bF[nc][0], acc[2*(q)+1][nc], 0, 0, 0); \
      acc[2*(q)+1][nc] = __builtin_amdgcn_mfma_i32_16x16x64_i8(R[3], bF[nc][1], acc[2*(q)+1][nc], 0, 0, 0); } }

#define BAR __builtin_amdgcn_s_barrier()

  // One K-tile. aP holds Q0 frags (loaded during the PREVIOUS tile; global
  // loads ride across the barrier, waited by counted vmcnt at first use).
  // Each quarter's loads issue one quarter ahead of their consuming MFMAs.
#define TILE_BODY(BUF, KCUR, KNEXT, PB) do { \
    GL_B(0, PB); GL_B(1, PB); \
    LOAD_B(BUF); \
    AL(aQ, 2, KCUR); \
    __builtin_amdgcn_s_setprio(1); MFMA_Q(0, aP); __builtin_amdgcn_s_setprio(0); \
    GL_B(2, PB); GL_B(3, PB); \
    AL(aP, 4, KCUR); \
    __builtin_amdgcn_s_setprio(1); MFMA_Q(1, aQ); __builtin_amdgcn_s_setprio(0); \
    AL(aQ, 6, KCUR); \
    __builtin_amdgcn_s_setprio(1); MFMA_Q(2, aP); __builtin_amdgcn_s_setprio(0); \
    WR_B(BUF^1); \
    AL(aP, 0, KNEXT); \
    __builtin_amdgcn_s_setprio(1); MFMA_Q(3, aQ); __builtin_amdgcn_s_setprio(0); \
    asm volatile("s_waitcnt lgkmcnt(0)" ::: "memory"); \
    BAR; \
  } while (0)

  // ---- prologue: stage B tile 0, prefetch A Q0 of tile 0 ----
  GL_B(0, bGl); GL_B(1, bGl); GL_B(2, bGl); GL_B(3, bGl);
  AL(aP, 0, 0);
  WR_B(0);                                   // compiler inserts counted vmcnt for sB
  asm volatile("s_waitcnt lgkmcnt(0)" ::: "memory");
  BAR;
  __builtin_amdgcn_sched_barrier(0);

  // ---- main loop: 2 K-tiles per iteration, compile-time buffer selection ----
  const signed char* bGk = bGl;
  int koff = 0;
  for (int it = 0; it < NT / 2 - 1; ++it) {
    TILE_BODY(0, koff,       koff + BKB,     bGk + BKB);       // tile 2it
    TILE_BODY(1, koff + BKB, koff + 2 * BKB, bGk + 2 * BKB);   // tile 2it+1
    koff += 2 * BKB; bGk += 2 * BKB;
  }
  TILE_BODY(0, koff, koff + BKB, bGk + BKB);         // tile 30, prefetch 31
  TILE_BODY(1, koff + BKB, koff + BKB, bGk + BKB);   // tile 31 (dead re-prefetch, in-bounds)

  // ---- epilogue: out = acc * (clamped_act_scale * alpha) + bias ----
  const float sA_ = fmaxf(act_scale_p[0], 1e-5f) * alpha_p[0];
  const int gn0 = bn * BN + wn * 64 + l15;
  const int gm0 = bm * BM + wm * 128 + l4 * 4;
#pragma unroll
  for (int nc = 0; nc < 4; ++nc) {
    const float bv = bias[gn0 + nc * 16];
#pragma unroll
    for (int mr = 0; mr < 8; ++mr) {
#pragma unroll
      for (int r = 0; r < 4; ++r) {
        const int gm = gm0 + mr * 16 + r;          // C/D: col=lane&15, row=(lane>>4)*4+reg
        out[(size_t)gm * N_DIM + gn0 + nc * 16] = (float)acc[mr][nc][r] * sA_ + bv;
      }
    }
  }
}

extern "C" void kernel_launch(void* const* d_in, const int* in_sizes, int n_in,
                              void* d_out, int out_size, void* d_ws, size_t ws_size,
                              hipStream_t stream) {
  const float* x      = (const float*)d_in[0];
  const int*   pw     = (const int*)d_in[1];
  const float* alpha  = (const float*)d_in[2];
  const float* act_sc = (const float*)d_in[3];
  const float* bias   = (const float*)d_in[4];
  float* out = (float*)d_out;

  signed char* x8 = (signed char*)d_ws;                          // 64 MiB
  signed char* w8 = (signed char*)d_ws + (size_t)M_DIM * K_DIM;  // 16 MiB

  quant_x_kernel<<<2048, 256, 0, stream>>>((const float4*)x, (int*)x8, act_sc, M_DIM * K_DIM / 4);
  pack_w_kernel<<<2048, 256, 0, stream>>>((const int4*)pw, (int*)w8, N_DIM * K_DIM / 4);

  dim3 grid((M_DIM / BM) * (N_DIM / BN));   // 1024 blocks, 1-D for XCD swizzle
  bitlinear_gemm<<<grid, 512, 0, stream>>>(x8, w8, bias, alpha, act_sc, out);
}

// Round 3
// 402.829 us; speedup vs baseline: 1.6614x; 1.6614x over previous
//
#include <hip/hip_runtime.h>
#include <hip/hip_bf16.h>

typedef int v4i __attribute__((ext_vector_type(4)));

#define M_DIM 16384
#define N_DIM 4096
#define K_DIM 4096
#define BM 256
#define BN 256
#define BKB 128                 // K-bytes per tile
#define NT (K_DIM / BKB)        // 32 K-tiles

// ---------------- activation fake-quant: f32 -> i8 ----------------
__global__ void quant_x_kernel(const float4* __restrict__ x, int* __restrict__ q,
                               const float* __restrict__ act_scale, int n4) {
  const float s = fmaxf(act_scale[0], 1e-5f);
  int i = blockIdx.x * blockDim.x + threadIdx.x;
  const int stride = gridDim.x * blockDim.x;
  for (; i < n4; i += stride) {
    float4 v = x[i];
    int b0 = (int)fminf(fmaxf(rintf(v.x / s), -127.f), 127.f);
    int b1 = (int)fminf(fmaxf(rintf(v.y / s), -127.f), 127.f);
    int b2 = (int)fminf(fmaxf(rintf(v.z / s), -127.f), 127.f);
    int b3 = (int)fminf(fmaxf(rintf(v.w / s), -127.f), 127.f);
    q[i] = (b0 & 0xff) | ((b1 & 0xff) << 8) | ((b2 & 0xff) << 16) | ((b3 & 0xff) << 24);
  }
}

// ---------------- ternary weight repack: i32 {0,1,2} -> i8 {-1,0,1} ----------------
__global__ void pack_w_kernel(const int4* __restrict__ w, int* __restrict__ q, int n4) {
  int i = blockIdx.x * blockDim.x + threadIdx.x;
  const int stride = gridDim.x * blockDim.x;
  for (; i < n4; i += stride) {
    int4 v = w[i];
    q[i] = ((v.x - 1) & 0xff) | (((v.y - 1) & 0xff) << 8) |
           (((v.z - 1) & 0xff) << 16) | (((v.w - 1) & 0xff) << 24);
  }
}

// ---- i8 GEMM. r2 post-mortem: A-direct-from-L2 failed on in-order vmcnt
// entanglement (every A wait transitively waited B's HBM latency) and L2 BW
// (A dup = 4GiB through L2 >= 116us vs LDS 69TB/s). REVERT to r1's LDS-A.
// THIS ROUND: replace reg-staging (GL->VGPR->ds_write, 64 ds_write_b128 =
// 768cyc/tile on the binding LDS pipe + pre-barrier vmcnt->write->lgkm tail)
// with global_load_lds DMA. The XOR store-swizzle p = c ^ (row&7) over 8-row
// 1KiB segments is a pure LANE permutation of the global SOURCE: lane l of a
// segment reads row l>>3, chunk (l&7)^(l>>3); DMA writes LDS linearly at
// base + l*16 -> stored layout is BIT-IDENTICAL to r1's verified layout, so
// every fragment-read address below is unchanged. Anti-alias hedge: four
// DISTINCT __shared__ objects (As0/As1/Bs0/Bs1) so SIInsertWaitcnts can prove
// in-flight DMA (writes tile t+1's buffers) never aliases this tile's
// ds_reads. DMAs issue at tile top (full-tile slack ~2300cyc >> 900cyc HBM);
// single vmcnt(0)+lgkmcnt(0) drain at the tile-end barrier (cross-wave
// visibility). New tile budget: LDS 192 reads ~2304cyc ~= MFMA 2342cyc.
__global__ __launch_bounds__(512, 2) void bitlinear_gemm(
    const signed char* __restrict__ A,   // [M][K] i8
    const signed char* __restrict__ B,   // [N][K] i8
    const float* __restrict__ bias,
    const float* __restrict__ alpha_p,
    const float* __restrict__ act_scale_p,
    float* __restrict__ out) {
  __shared__ __align__(16) signed char As0[BM * BKB];   // 32 KiB each,
  __shared__ __align__(16) signed char As1[BM * BKB];   // distinct objects
  __shared__ __align__(16) signed char Bs0[BN * BKB];   // (alias-precision
  __shared__ __align__(16) signed char Bs1[BN * BKB];   //  for waitcnt pass)

  const int t = threadIdx.x;
  const int lane = t & 63, wid = t >> 6;
  const int wm = wid >> 2, wn = wid & 3;       // 2M x 4N waves
  const int l15 = lane & 15, l4 = lane >> 4;

  // XCD-aware bijective swizzle (nwg=1024, divisible by 8)
  const int nwg = (M_DIM / BM) * (N_DIM / BN);
  const int wg = (blockIdx.x & 7) * (nwg >> 3) + (blockIdx.x >> 3);
  const int bm = wg / (N_DIM / BN);
  const int bn = wg % (N_DIM / BN);

  // ---- DMA staging: wave w owns 4 x 1KiB segments = rows 32w..32w+31.
  // Segment s=(4w+i): LDS bytes s*1024.. (rows 8s..8s+7, linear, lane*16);
  // global source lane l: row 8s + (l>>3), chunk (l&7)^(l>>3) (pre-swizzled).
  const int dmaSeg = wid * 4096;               // LDS byte base of segment 4w
  const signed char* aD = A + ((size_t)(bm * BM + 32 * wid + (lane >> 3))) * K_DIM
                            + (((lane & 7) ^ (lane >> 3)) * 16);
  const signed char* bD = B + ((size_t)(bn * BN + 32 * wid + (lane >> 3))) * K_DIM
                            + (((lane & 7) ^ (lane >> 3)) * 16);

#define DMA4(SRCBASE, DSTARR, KOFF) \
  { _Pragma("unroll") for (int i = 0; i < 4; ++i) \
      __builtin_amdgcn_global_load_lds( \
        (const __attribute__((address_space(1))) void*)((SRCBASE) + (size_t)(8 * i) * K_DIM + (KOFF)), \
        (__attribute__((address_space(3))) void*)(&(DSTARR)[dmaSeg + i * 1024]), \
        16, 0, 0); }

  // ---- fragment read addressing (unchanged from r1: zero-conflict) ----
  const int l7 = l15 & 7;
  const int soK0 = ((0 + l4) ^ l7) * 16;   // kstep 0 chunk
  const int soK1 = ((4 + l4) ^ l7) * 16;   // kstep 1 chunk
  const int aRd = (wm * 128 + l15) * BKB;
  const int bRd = (wn * 64 + l15) * BKB;

  v4i acc[8][4] = {};
  v4i bF[4][2], aF[2][2];

#define LOAD_B(BS) \
  { _Pragma("unroll") for (int nc = 0; nc < 4; ++nc) { \
      bF[nc][0] = *(const v4i*)&(BS)[bRd + nc * 2048 + soK0]; \
      bF[nc][1] = *(const v4i*)&(BS)[bRd + nc * 2048 + soK1]; } }

#define LOAD_A(AS, q) \
  aF[0][0] = *(const v4i*)&(AS)[aRd + (2*(q)) * 2048 + soK0]; \
  aF[0][1] = *(const v4i*)&(AS)[aRd + (2*(q)) * 2048 + soK1]; \
  aF[1][0] = *(const v4i*)&(AS)[aRd + (2*(q)+1) * 2048 + soK0]; \
  aF[1][1] = *(const v4i*)&(AS)[aRd + (2*(q)+1) * 2048 + soK1];

#define MFMA_Q(q) \
  { _Pragma("unroll") for (int nc = 0; nc < 4; ++nc) { \
      acc[2*(q)][nc]   = __builtin_amdgcn_mfma_i32_16x16x64_i8(aF[0][0], bF[nc][0], acc[2*(q)][nc], 0, 0, 0); \
      acc[2*(q)][nc]   = __builtin_amdgcn_mfma_i32_16x16x64_i8(aF[0][1], bF[nc][1], acc[2*(q)][nc], 0, 0, 0); \
      acc[2*(q)+1][nc] = __builtin_amdgcn_mfma_i32_16x16x64_i8(aF[1][0], bF[nc][0], acc[2*(q)+1][nc], 0, 0, 0); \
      acc[2*(q)+1][nc] = __builtin_amdgcn_mfma_i32_16x16x64_i8(aF[1][1], bF[nc][1], acc[2*(q)+1][nc], 0, 0, 0); } }

#define BAR __builtin_amdgcn_s_barrier()

  // One K-tile: DMA next tile at top (max slack), 4 read+MFMA quarters with
  // no intra-tile barriers (r1 structure), single drain+barrier at the flip.
#define TILE_BODY(ASR, BSR, ASW, BSW, KNEXT) do { \
    DMA4(bD, BSW, KNEXT); \
    DMA4(aD, ASW, KNEXT); \
    LOAD_B(BSR); LOAD_A(ASR, 0); \
    __builtin_amdgcn_s_setprio(1); MFMA_Q(0); __builtin_amdgcn_s_setprio(0); \
    LOAD_A(ASR, 1); \
    __builtin_amdgcn_s_setprio(1); MFMA_Q(1); __builtin_amdgcn_s_setprio(0); \
    LOAD_A(ASR, 2); \
    __builtin_amdgcn_s_setprio(1); MFMA_Q(2); __builtin_amdgcn_s_setprio(0); \
    LOAD_A(ASR, 3); \
    __builtin_amdgcn_s_setprio(1); MFMA_Q(3); __builtin_amdgcn_s_setprio(0); \
    asm volatile("s_waitcnt vmcnt(0) lgkmcnt(0)" ::: "memory"); \
    BAR; \
  } while (0)

  // ---- prologue: DMA tile 0 into buf0 ----
  DMA4(bD, Bs0, 0);
  DMA4(aD, As0, 0);
  asm volatile("s_waitcnt vmcnt(0)" ::: "memory");
  BAR;
  __builtin_amdgcn_sched_barrier(0);

  // ---- main loop: 2 K-tiles per iteration, compile-time buffer selection ----
  for (int it = 0; it < NT / 2 - 1; ++it) {
    TILE_BODY(As0, Bs0, As1, Bs1, (2 * it + 1) * BKB);   // tile 2it,   load 2it+1
    TILE_BODY(As1, Bs1, As0, Bs0, (2 * it + 2) * BKB);   // tile 2it+1, load 2it+2
  }
  TILE_BODY(As0, Bs0, As1, Bs1, 31 * BKB);   // tile 30, load 31
  TILE_BODY(As1, Bs1, As0, Bs0, 31 * BKB);   // tile 31, dead re-load (in-bounds)

  // ---- epilogue: out = acc * (clamped_act_scale * alpha) + bias ----
  const float sA_ = fmaxf(act_scale_p[0], 1e-5f) * alpha_p[0];
  const int gn0 = bn * BN + wn * 64 + l15;
  const int gm0 = bm * BM + wm * 128 + l4 * 4;
#pragma unroll
  for (int nc = 0; nc < 4; ++nc) {
    const float bv = bias[gn0 + nc * 16];
#pragma unroll
    for (int mr = 0; mr < 8; ++mr) {
#pragma unroll
      for (int r = 0; r < 4; ++r) {
        const int gm = gm0 + mr * 16 + r;          // C/D: col=lane&15, row=(lane>>4)*4+reg
        out[(size_t)gm * N_DIM + gn0 + nc * 16] = (float)acc[mr][nc][r] * sA_ + bv;
      }
    }
  }
}

extern "C" void kernel_launch(void* const* d_in, const int* in_sizes, int n_in,
                              void* d_out, int out_size, void* d_ws, size_t ws_size,
                              hipStream_t stream) {
  const float* x      = (const float*)d_in[0];
  const int*   pw     = (const int*)d_in[1];
  const float* alpha  = (const float*)d_in[2];
  const float* act_sc = (const float*)d_in[3];
  const float* bias   = (const float*)d_in[4];
  float* out = (float*)d_out;

  signed char* x8 = (signed char*)d_ws;                          // 64 MiB
  signed char* w8 = (signed char*)d_ws + (size_t)M_DIM * K_DIM;  // 16 MiB

  quant_x_kernel<<<2048, 256, 0, stream>>>((const float4*)x, (int*)x8, act_sc, M_DIM * K_DIM / 4);
  pack_w_kernel<<<2048, 256, 0, stream>>>((const int4*)pw, (int*)w8, N_DIM * K_DIM / 4);

  dim3 grid((M_DIM / BM) * (N_DIM / BN));   // 1024 blocks, 1-D for XCD swizzle
  bitlinear_gemm<<<grid, 512, 0, stream>>>(x8, w8, bias, alpha, act_sc, out);
}

// Round 4
// 381.782 us; speedup vs baseline: 1.7530x; 1.0551x over previous
//
#include <hip/hip_runtime.h>
#include <hip/hip_bf16.h>

typedef int v4i __attribute__((ext_vector_type(4)));

#define M_DIM 16384
#define N_DIM 4096
#define K_DIM 4096
#define BM 256
#define BN 256
#define BKB 128                 // K-bytes per tile
#define NT (K_DIM / BKB)        // 32 K-tiles

// ---------------- activation fake-quant: f32 -> i8 ----------------
__global__ void quant_x_kernel(const float4* __restrict__ x, int* __restrict__ q,
                               const float* __restrict__ act_scale, int n4) {
  const float s = fmaxf(act_scale[0], 1e-5f);
  int i = blockIdx.x * blockDim.x + threadIdx.x;
  const int stride = gridDim.x * blockDim.x;
  for (; i < n4; i += stride) {
    float4 v = x[i];
    int b0 = (int)fminf(fmaxf(rintf(v.x / s), -127.f), 127.f);
    int b1 = (int)fminf(fmaxf(rintf(v.y / s), -127.f), 127.f);
    int b2 = (int)fminf(fmaxf(rintf(v.z / s), -127.f), 127.f);
    int b3 = (int)fminf(fmaxf(rintf(v.w / s), -127.f), 127.f);
    q[i] = (b0 & 0xff) | ((b1 & 0xff) << 8) | ((b2 & 0xff) << 16) | ((b3 & 0xff) << 24);
  }
}

// ---------------- ternary weight repack: i32 {0,1,2} -> i8 {-1,0,1} ----------------
__global__ void pack_w_kernel(const int4* __restrict__ w, int* __restrict__ q, int n4) {
  int i = blockIdx.x * blockDim.x + threadIdx.x;
  const int stride = gridDim.x * blockDim.x;
  for (; i < n4; i += stride) {
    int4 v = w[i];
    q[i] = ((v.x - 1) & 0xff) | (((v.y - 1) & 0xff) << 8) |
           (((v.z - 1) & 0xff) << 16) | (((v.w - 1) & 0xff) << 24);
  }
}

// ---- i8 GEMM. r3 post-mortem: global_load_lds DMA regressed (compiler's
// waitcnt pass treats DMA as clobbering all LDS -> vmcnt injected before
// same-tile ds_reads). REVERTED to r1 reg-staging. THIS ROUND: half-quarter
// FRAGMENT ROTATION. r1's limit: 2 waves/SIMD (reg cap) + LOAD_A(q)
// immediately feeding MFMA_Q(q) => ~350cyc contended-LDS wait at every
// quarter, pipes near-serialize (5344cyc/tile vs LDS 3072 / MFMA 2611).
// Rotation: quarter -> two 8-MFMA halves; half h uses only aF(h&1); after the
// last MFMA sourcing a buffer, that buffer is dead -> issue msub h+2's reads
// into it, compute other half meanwhile. Operands now arrive ~1 half (~300+
// SIMD-cyc) ahead of use for halves 1..7; only the post-barrier cold start
// stays exposed. Register budget identical to r1 (aF0/aF1 = 16 regs).
__global__ __launch_bounds__(512, 2) void bitlinear_gemm(
    const signed char* __restrict__ A,   // [M][K] i8
    const signed char* __restrict__ B,   // [N][K] i8
    const float* __restrict__ bias,
    const float* __restrict__ alpha_p,
    const float* __restrict__ act_scale_p,
    float* __restrict__ out) {
  __shared__ __align__(16) signed char As[2][BM * BKB];   // 2 x 32 KiB
  __shared__ __align__(16) signed char Bs[2][BN * BKB];   // 2 x 32 KiB

  const int t = threadIdx.x;
  const int lane = t & 63, wid = t >> 6;
  const int wm = wid >> 2, wn = wid & 3;       // 2M x 4N waves
  const int l15 = lane & 15, l4 = lane >> 4;

  // XCD-aware bijective swizzle (nwg=1024, divisible by 8)
  const int nwg = (M_DIM / BM) * (N_DIM / BN);
  const int wg = (blockIdx.x & 7) * (nwg >> 3) + (blockIdx.x >> 3);
  const int bm = wg / (N_DIM / BN);
  const int bn = wg % (N_DIM / BN);

  // ---- reg-staging addressing: LINEAR global loads, SWIZZLED ds_write ----
  const signed char* aGl = A + ((size_t)(bm * BM + (t >> 3))) * K_DIM + (t & 7) * 16;
  const signed char* bGl = B + ((size_t)(bn * BN + (t >> 3))) * K_DIM + (t & 7) * 16;
  // LDS write offset: row*128 + (chunk ^ (row&7))*16   (stored layout unchanged)
  const int wrOff = (t >> 3) * 128 + (((t & 7) ^ ((t >> 3) & 7)) * 16);

  v4i sA[4], sB[4];   // staging registers (one tile in flight)

#define GL_A(u, P) sA[u] = *(const v4i*)((P) + (size_t)((u) * 64) * K_DIM)
#define GL_B(u, P) sB[u] = *(const v4i*)((P) + (size_t)((u) * 64) * K_DIM)
#define WR_A(BUF) { _Pragma("unroll") for (int u = 0; u < 4; ++u) \
    *(v4i*)&As[BUF][u * 8192 + wrOff] = sA[u]; }
#define WR_B(BUF) { _Pragma("unroll") for (int u = 0; u < 4; ++u) \
    *(v4i*)&Bs[BUF][u * 8192 + wrOff] = sB[u]; }

  // ---- fragment read addressing (zero-conflict XOR layout) ----
  const int l7 = l15 & 7;
  const int soK0 = ((0 + l4) ^ l7) * 16;   // kstep 0 chunk
  const int soK1 = ((4 + l4) ^ l7) * 16;   // kstep 1 chunk
  const int aRd = (wm * 128 + l15) * BKB;
  const int bRd = (wn * 64 + l15) * BKB;

  v4i acc[8][4] = {};
  v4i bF[4][2];
  v4i aF0[2], aF1[2];          // rotating A-fragment buffers (named: static idx)

#define LOAD_B(buf) \
  { _Pragma("unroll") for (int nc = 0; nc < 4; ++nc) { \
      bF[nc][0] = *(const v4i*)&Bs[buf][bRd + nc * 2048 + soK0]; \
      bF[nc][1] = *(const v4i*)&Bs[buf][bRd + nc * 2048 + soK1]; } }

  // load A fragments for m-subtile m into rotation buffer R
#define LOAD_A2(buf, m, R) \
  R[0] = *(const v4i*)&As[buf][aRd + (m) * 2048 + soK0]; \
  R[1] = *(const v4i*)&As[buf][aRd + (m) * 2048 + soK1];

  // 8 MFMAs: m-subtile h against all 4 n-columns (acc[h] <-> rows h*16..h*16+15)
#define HALF(h, R) \
  { _Pragma("unroll") for (int nc = 0; nc < 4; ++nc) { \
      acc[h][nc] = __builtin_amdgcn_mfma_i32_16x16x64_i8(R[0], bF[nc][0], acc[h][nc], 0, 0, 0); \
      acc[h][nc] = __builtin_amdgcn_mfma_i32_16x16x64_i8(R[1], bF[nc][1], acc[h][nc], 0, 0, 0); } }

#define BAR __builtin_amdgcn_s_barrier()
#define PRIO1 __builtin_amdgcn_s_setprio(1)
#define PRIO0 __builtin_amdgcn_s_setprio(0)

  // One K-tile: cold-start reads, then 8 halves with rotated A prefetch.
  // Staging GLs spread across early halves (slack to WR >= 3 halves); WRs hit
  // the write buffer only; single lgkmcnt(0)+barrier at the flip.
#define TILE_BODY(BUF, PA, PB) do { \
    LOAD_A2(BUF, 0, aF0); \
    LOAD_B(BUF); \
    LOAD_A2(BUF, 1, aF1); \
    GL_B(0, PB); GL_B(1, PB); \
    PRIO1; HALF(0, aF0); PRIO0; \
    LOAD_A2(BUF, 2, aF0); \
    GL_B(2, PB); GL_B(3, PB); \
    PRIO1; HALF(1, aF1); PRIO0; \
    LOAD_A2(BUF, 3, aF1); \
    PRIO1; HALF(2, aF0); PRIO0; \
    LOAD_A2(BUF, 4, aF0); \
    GL_A(0, PA); GL_A(1, PA); \
    PRIO1; HALF(3, aF1); PRIO0; \
    LOAD_A2(BUF, 5, aF1); \
    GL_A(2, PA); GL_A(3, PA); \
    PRIO1; HALF(4, aF0); PRIO0; \
    WR_B(BUF^1); \
    LOAD_A2(BUF, 6, aF0); \
    PRIO1; HALF(5, aF1); PRIO0; \
    LOAD_A2(BUF, 7, aF1); \
    PRIO1; HALF(6, aF0); PRIO0; \
    WR_A(BUF^1); \
    PRIO1; HALF(7, aF1); PRIO0; \
    asm volatile("s_waitcnt lgkmcnt(0)" ::: "memory"); \
    BAR; \
  } while (0)

  // ---- prologue: load + write tile 0 ----
  GL_B(0, bGl); GL_B(1, bGl); GL_B(2, bGl); GL_B(3, bGl);
  GL_A(0, aGl); GL_A(1, aGl); GL_A(2, aGl); GL_A(3, aGl);
  asm volatile("s_waitcnt vmcnt(0)" ::: "memory");
  WR_B(0); WR_A(0);
  asm volatile("s_waitcnt lgkmcnt(0)" ::: "memory");
  BAR;
  __builtin_amdgcn_sched_barrier(0);

  // ---- main loop: 2 K-tiles per iteration, compile-time buffer selection ----
  const signed char* aGk = aGl;
  const signed char* bGk = bGl;
  for (int it = 0; it < NT / 2 - 1; ++it) {
    TILE_BODY(0, aGk + BKB,     bGk + BKB);       // tile 2it,   load 2it+1
    TILE_BODY(1, aGk + 2 * BKB, bGk + 2 * BKB);   // tile 2it+1, load 2it+2
    aGk += 2 * BKB; bGk += 2 * BKB;
  }
  TILE_BODY(0, aGk + BKB, bGk + BKB);             // tile 30, load 31
  TILE_BODY(1, aGk + BKB, bGk + BKB);             // tile 31, re-load 31 (dead write to buf0)

  // ---- epilogue: out = acc * (clamped_act_scale * alpha) + bias ----
  const float sA_ = fmaxf(act_scale_p[0], 1e-5f) * alpha_p[0];
  const int gn0 = bn * BN + wn * 64 + l15;
  const int gm0 = bm * BM + wm * 128 + l4 * 4;
#pragma unroll
  for (int nc = 0; nc < 4; ++nc) {
    const float bv = bias[gn0 + nc * 16];
#pragma unroll
    for (int mr = 0; mr < 8; ++mr) {
#pragma unroll
      for (int r = 0; r < 4; ++r) {
        const int gm = gm0 + mr * 16 + r;          // C/D: col=lane&15, row=(lane>>4)*4+reg
        out[(size_t)gm * N_DIM + gn0 + nc * 16] = (float)acc[mr][nc][r] * sA_ + bv;
      }
    }
  }
}

extern "C" void kernel_launch(void* const* d_in, const int* in_sizes, int n_in,
                              void* d_out, int out_size, void* d_ws, size_t ws_size,
                              hipStream_t stream) {
  const float* x      = (const float*)d_in[0];
  const int*   pw     = (const int*)d_in[1];
  const float* alpha  = (const float*)d_in[2];
  const float* act_sc = (const float*)d_in[3];
  const float* bias   = (const float*)d_in[4];
  float* out = (float*)d_out;

  signed char* x8 = (signed char*)d_ws;                          // 64 MiB
  signed char* w8 = (signed char*)d_ws + (size_t)M_DIM * K_DIM;  // 16 MiB

  quant_x_kernel<<<2048, 256, 0, stream>>>((const float4*)x, (int*)x8, act_sc, M_DIM * K_DIM / 4);
  pack_w_kernel<<<2048, 256, 0, stream>>>((const int4*)pw, (int*)w8, N_DIM * K_DIM / 4);

  dim3 grid((M_DIM / BM) * (N_DIM / BN));   // 1024 blocks, 1-D for XCD swizzle
  bitlinear_gemm<<<grid, 512, 0, stream>>>(x8, w8, bias, alpha, act_sc, out);
}